// Round 1
// baseline (726.679 us; speedup 1.0000x reference)
//
#include <hip/hip_runtime.h>

#define TAU 0.25f
#define SIGMA 0.5f

constexpr int H = 1024, W = 1024, C = 3;
constexpr int N = H * W * C;      // 3,145,728 elements
constexpr int WC = W * C;         // row stride in elements

// --- init: u = ubar = di; p = 0; tb = TAU*dc*db; rc = 1/(1+TAU*dc) ---
__global__ void tv_init(const float* __restrict__ dc, const float* __restrict__ db,
                        const float* __restrict__ di,
                        float* __restrict__ u, float* __restrict__ ubar,
                        float* __restrict__ px, float* __restrict__ py,
                        float* __restrict__ tb, float* __restrict__ rc) {
    int i = blockIdx.x * blockDim.x + threadIdx.x;
    if (i >= N) return;
    float v = di[i];
    u[i] = v;
    ubar[i] = v;
    px[i] = 0.0f;
    py[i] = 0.0f;
    float c = dc[i];
    tb[i] = TAU * c * db[i];
    rc[i] = 1.0f / (1.0f + TAU * c);
}

// --- dual: p = clip(p + SIGMA*grad(ubar), -w, w) (forward diff, Neumann) ---
__global__ void tv_dual(const float* __restrict__ ubar,
                        float* __restrict__ px, float* __restrict__ py,
                        const float* __restrict__ wx, const float* __restrict__ wy) {
    int i = blockIdx.x * blockDim.x + threadIdx.x;
    if (i >= N) return;
    int xc = i % WC;          // x*C + c within row
    int y  = i / WC;
    float ub = ubar[i];
    float gx = (xc < WC - C) ? (ubar[i + C]  - ub) : 0.0f;
    float gy = (y  < H - 1)  ? (ubar[i + WC] - ub) : 0.0f;
    float ax = wx[i];
    float ay = wy[i];
    float pxv = px[i] + SIGMA * gx;
    pxv = fminf(fmaxf(pxv, -ax), ax);
    float pyv = py[i] + SIGMA * gy;
    pyv = fminf(fmaxf(pyv, -ay), ay);
    px[i] = pxv;
    py[i] = pyv;
}

// --- primal: u_new = (u + TAU*div(p) + tb) * rc;  ubar = 2*u_new - u ---
__global__ void tv_primal(float* __restrict__ u, float* __restrict__ ubar,
                          const float* __restrict__ px, const float* __restrict__ py,
                          const float* __restrict__ tb, const float* __restrict__ rc) {
    int i = blockIdx.x * blockDim.x + threadIdx.x;
    if (i >= N) return;
    int xc = i % WC;
    int y  = i / WC;
    float d = px[i] + py[i];
    if (xc >= C) d -= px[i - C];   // backward diff in x
    if (y  >= 1) d -= py[i - WC];  // backward diff in y
    float uo = u[i];
    float un = (uo + TAU * d + tb[i]) * rc[i];
    u[i] = un;
    ubar[i] = 2.0f * un - uo;
}

extern "C" void kernel_launch(void* const* d_in, const int* in_sizes, int n_in,
                              void* d_out, int out_size, void* d_ws, size_t ws_size,
                              hipStream_t stream) {
    const float* t_dx = (const float*)d_in[0];
    const float* t_dy = (const float*)d_in[1];
    const float* t_dc = (const float*)d_in[2];
    const float* t_db = (const float*)d_in[3];
    const float* t_di = (const float*)d_in[4];
    // d_in[5] = its (20), d_in[6] = pid — Python scalars fixed by setup_inputs.
    const int its = 20;

    float* u    = (float*)d_out;            // final result lives here, HWC layout
    float* ws   = (float*)d_ws;
    float* ubar = ws + 0L * N;
    float* px   = ws + 1L * N;
    float* py   = ws + 2L * N;
    float* tb   = ws + 3L * N;
    float* rc   = ws + 4L * N;

    const int threads = 256;
    const int blocks = (N + threads - 1) / threads;

    tv_init<<<blocks, threads, 0, stream>>>(t_dc, t_db, t_di, u, ubar, px, py, tb, rc);

    for (int it = 0; it < its; ++it) {
        tv_dual<<<blocks, threads, 0, stream>>>(ubar, px, py, t_dx, t_dy);
        tv_primal<<<blocks, threads, 0, stream>>>(u, ubar, px, py, tb, rc);
    }
}